// Round 11
// baseline (191.002 us; speedup 1.0000x reference)
//
#include <hip/hip_runtime.h>
#include <math.h>

#define N_NODES 3000
#define T_STEPS 12
#define F_INP 2
#define HEADS 8
#define HID 32
#define E_EDGES 32000
#define E_TOT (E_EDGES + N_NODES)   // 35000 with self-loops
#define NEG_SLOPE 0.2f
#define OUT_F 24                    // F_OUT * T_OUT
#define CHUNKS 8                    // 8 slots x 8 chunks = 64 edges in regs
#define NT (N_NODES * T_STEPS)      // 36000
#define WROW 33                     // LDS row stride (+1 pad -> conflict-free)

__device__ __forceinline__ float sigm(float x) {
    return 1.0f / (1.0f + __expf(-x));
}
__device__ __forceinline__ float tanh_f(float x) {
    return 1.0f - 2.0f / (__expf(2.0f * x) + 1.0f);
}
// broadcast lane l's value via scalar pipe (v_readlane). CONVERGENT: call at
// full exec only (round-4 post-mortem).
__device__ __forceinline__ float rdlane(float v, int l) {
    return __int_as_float(__builtin_amdgcn_readlane(__float_as_int(v), l));
}

// ---------------------------------------------------------------------------
// k_graph: ONE launch replacing k_init/k_deg/k_scan/k_scatter (round-10
// lesson: ~70 us of wall time was tiny CSR kernels + 7 serial launch gaps).
// block 0: full CSR build in LDS (histogram -> shfl scan -> scatter);
// blocks 1..36: Xt[t][n] transpose; block 37: proj coefficients.
// ---------------------------------------------------------------------------
__global__ __launch_bounds__(1024) void k_graph(const int* __restrict__ ei,
                                                const float* __restrict__ X,
                                                const float* __restrict__ gat_w,
                                                const float* __restrict__ att_src,
                                                const float* __restrict__ att_dst,
                                                float2* __restrict__ Xt,
                                                float* __restrict__ proj,
                                                int* __restrict__ row_start,
                                                int* __restrict__ csr_src) {
    int tid = threadIdx.x, b = blockIdx.x;
    if (b == 0) {
        __shared__ int sdeg[N_NODES];    // 12 KB: deg, then cursor
        __shared__ int wsum[17];
        for (int i = tid; i < N_NODES; i += 1024) sdeg[i] = 0;
        __syncthreads();
        for (int i = tid; i < E_TOT; i += 1024) {
            int d = (i < E_EDGES) ? ei[E_EDGES + i] : (i - E_EDGES);
            atomicAdd(&sdeg[d], 1);
        }
        __syncthreads();
        // exclusive scan: 3 nodes per thread, wave shfl-scan, 16 wave partials
        int base = tid * 3;
        int d0 = (base     < N_NODES) ? sdeg[base]     : 0;
        int d1 = (base + 1 < N_NODES) ? sdeg[base + 1] : 0;
        int d2 = (base + 2 < N_NODES) ? sdeg[base + 2] : 0;
        int s = d0 + d1 + d2;
        int incl = s;
        #pragma unroll
        for (int dlt = 1; dlt < 64; dlt <<= 1) {
            int v = __shfl_up(incl, dlt, 64);
            if ((tid & 63) >= dlt) incl += v;
        }
        int wid = tid >> 6;
        if ((tid & 63) == 63) wsum[wid] = incl;
        __syncthreads();
        if (tid == 0) {
            int run = 0;
            #pragma unroll
            for (int w = 0; w < 16; w++) { int t2 = wsum[w]; wsum[w] = run; run += t2; }
        }
        __syncthreads();
        int off = wsum[wid] + (incl - s);
        if (base     < N_NODES) { row_start[base]     = off;           sdeg[base]     = off; }
        if (base + 1 < N_NODES) { row_start[base + 1] = off + d0;      sdeg[base + 1] = off + d0; }
        if (base + 2 < N_NODES) { row_start[base + 2] = off + d0 + d1; sdeg[base + 2] = off + d0 + d1; }
        if (tid == 0) row_start[N_NODES] = E_TOT;
        __syncthreads();
        for (int i = tid; i < E_TOT; i += 1024) {
            int s2, d;
            if (i < E_EDGES) { s2 = ei[i]; d = ei[E_EDGES + i]; }
            else             { s2 = i - E_EDGES; d = s2; }
            int pos = atomicAdd(&sdeg[d], 1);
            csr_src[pos] = s2;
        }
    } else if (b <= 36) {
        int i = (b - 1) * 1024 + tid;    // i = n*T + t
        if (i < NT) {
            int n = i / T_STEPS, t = i - n * T_STEPS;
            float2 v = *(const float2*)&X[(size_t)i * 2];
            Xt[(size_t)t * N_NODES + n] = v;
        }
    } else {
        if (tid < 32) {
            int h = tid & 7, w = tid >> 3;
            const float* att = (w < 2) ? att_src : att_dst;
            int f = w & 1;
            float s = 0.0f;
            for (int c = 0; c < 32; c++)
                s += gat_w[((h * 32 + c) * 2) + f] * att[h * 32 + c];
            proj[w * 8 + h] = s;
        }
    }
}

// ---------------------------------------------------------------------------
// k_gat: one wave64 per (t,n). lanes = 8 heads x 8 slots. Edge values in
// registers, reductions via shfl_xor(1,2,4); head-sum broadcast via
// v_readlane AT FULL EXEC. Reads Xt (L1-resident 24 KB plane per t).
// gat_out layout: [n][t][c]   (unchanged from round 10)
// ---------------------------------------------------------------------------
__global__ __launch_bounds__(256) void k_gat(const float2* __restrict__ Xt,
                                             const int* __restrict__ row_start,
                                             const int* __restrict__ csr_src,
                                             const float* __restrict__ proj,
                                             const float* __restrict__ gat_w,
                                             const float* __restrict__ gat_b,
                                             float* __restrict__ gat_out) {
    int pair = blockIdx.x * 4 + (threadIdx.x >> 6);   // t*N + n
    int t = pair / N_NODES, n = pair - t * N_NODES;
    int lane = threadIdx.x & 63;
    int h = lane >> 3, slot = lane & 7;
    int rs = row_start[n];
    int deg = row_start[n + 1] - rs;     // >= 1 (self-loop)
    const float2* Xp = Xt + (size_t)t * N_NODES;
    float ps0 = proj[h], ps1 = proj[8 + h];
    float pd0 = proj[16 + h], pd1 = proj[24 + h];
    float2 xd = Xp[n];
    float ad = fmaf(xd.x, pd0, xd.y * pd1);

    float x0c[CHUNKS], x1c[CHUNKS], sc[CHUNKS];
    float m = -1e30f;
    #pragma unroll
    for (int c = 0; c < CHUNKS; c++) {
        if (8 * c < deg) {                       // wave-uniform branch
            int e = slot + 8 * c;
            int idx = rs + (e < deg ? e : deg - 1);
            int src = csr_src[idx];
            float2 xv = Xp[src];
            x0c[c] = xv.x; x1c[c] = xv.y;
            float s = fmaf(xv.x, ps0, fmaf(xv.y, ps1, ad));
            s = (s > 0.0f) ? s : NEG_SLOPE * s;
            sc[c] = (e < deg) ? s : -1e30f;
            m = fmaxf(m, sc[c]);
        } else { x0c[c] = 0.0f; x1c[c] = 0.0f; sc[c] = -1e30f; }
    }
    // deg > 64 fallback (never taken for this graph; wave-uniform)
    for (int e = 64 + slot; e < deg; e += 8) {
        float2 xv = Xp[csr_src[rs + e]];
        float s = fmaf(xv.x, ps0, fmaf(xv.y, ps1, ad));
        s = (s > 0.0f) ? s : NEG_SLOPE * s;
        m = fmaxf(m, s);
    }
    m = fmaxf(m, __shfl_xor(m, 1, 64));
    m = fmaxf(m, __shfl_xor(m, 2, 64));
    m = fmaxf(m, __shfl_xor(m, 4, 64));

    float den = 0.0f, S0 = 0.0f, S1 = 0.0f;
    #pragma unroll
    for (int c = 0; c < CHUNKS; c++) {
        if (8 * c < deg) {
            float a = __expf(sc[c] - m);          // masked slots: exp(-1e30)=0
            den += a;
            S0 = fmaf(a, x0c[c], S0);
            S1 = fmaf(a, x1c[c], S1);
        }
    }
    for (int e = 64 + slot; e < deg; e += 8) {    // fallback recompute
        float2 xv = Xp[csr_src[rs + e]];
        float s = fmaf(xv.x, ps0, fmaf(xv.y, ps1, ad));
        s = (s > 0.0f) ? s : NEG_SLOPE * s;
        float a = __expf(s - m);
        den += a; S0 = fmaf(a, xv.x, S0); S1 = fmaf(a, xv.y, S1);
    }
    #pragma unroll
    for (int mm = 1; mm <= 4; mm <<= 1) {
        den += __shfl_xor(den, mm, 64);
        S0  += __shfl_xor(S0,  mm, 64);
        S1  += __shfl_xor(S1,  mm, 64);
    }
    float inv = 0.125f / den;
    float v0 = S0 * inv, v1 = S1 * inv;

    // per-head broadcasts at FULL EXEC (readlane is convergent; round-4 fix)
    float a0[HEADS], a1[HEADS];
    #pragma unroll
    for (int hh = 0; hh < HEADS; hh++) {
        a0[hh] = rdlane(v0, hh * 8);
        a1[hh] = rdlane(v1, hh * 8);
    }

    // branch-free projection: all lanes compute, lanes 0..31 store
    int cc = lane & 31;
    float acc = gat_b[cc];
    #pragma unroll
    for (int hh = 0; hh < HEADS; hh++) {
        float2 g = *(const float2*)&gat_w[(hh * 32 + cc) * 2];
        acc = fmaf(a0[hh], g.x, fmaf(a1[hh], g.y, acc));
    }
    if (lane < 32)
        gat_out[((size_t)n * T_STEPS + t) * HID + cc] = acc;
}

// ---------------------------------------------------------------------------
// k_lstm v5: v3 body (all state in registers, weights LDS-staged coalesced,
// 16.9 KB LDS) + amdgpu_waves_per_eu(3,3).
// Round-10 post-mortem: across v2(68)/v3(56)/v4(68) the allocator pinned
// arch VGPRs at ~64 (the 8-waves/SIMD point) and AGPR-shuffled the 64-float
// weight arrays (measured ~12.4k VALU instr/wave vs ~6k hand-count), and
// launch_bounds' min-waves arg did not move it. waves_per_eu(3,3) declares
// occupancy target = exactly 3 waves/SIMD (grid supplies 2.93) so the
// allocator may use the ~168-VGPR budget; ~124 live floats then fit in
// arch VGPRs with zero AGPR traffic. v4's 36 KB LDS state is dropped
// (53.7 KB/block had cut residency to 2 blocks/CU).
// ---------------------------------------------------------------------------
__global__ __launch_bounds__(256)
__attribute__((amdgpu_waves_per_eu(3, 3)))
void k_lstm(const float* __restrict__ gat_out,  // [n][t][32]
            const float* __restrict__ w_ih0,
            const float* __restrict__ w_hh0,
            const float* __restrict__ b_ih0,
            const float* __restrict__ b_hh0,
            const float* __restrict__ w_ih1,
            const float* __restrict__ w_hh1,
            const float* __restrict__ b_ih1,
            const float* __restrict__ b_hh1,
            const float* __restrict__ fc_w,
            const float* __restrict__ fc_b,
            float* __restrict__ out) {          // [n][24]
    __shared__ float wl[128 * WROW];            // 16.9 KB, reused 5x
    int tid = threadIdx.x;
    int lane = tid & 63;
    int n = blockIdx.x * 4 + (tid >> 6);
    int j = lane & 31, half = lane >> 5;
    int rowA = half * 64 + j;        // gate i (half0) / g (half1)
    int rowB = rowA + 32;            // gate f (half0) / o (half1)

    // coalesced global -> LDS stage (float4 loads, scalar LDS writes)
    auto stage = [&](const float* __restrict__ src, int nfloats) {
        for (int base = tid * 4; base < nfloats; base += 1024) {
            float4 v = *(const float4*)&src[base];
            float* d = &wl[(base >> 5) * WROW + (base & 31)];
            d[0] = v.x; d[1] = v.y; d[2] = v.z; d[3] = v.w;
        }
    };
    // per-lane row fetch from LDS (conflict-free: bank = (row+k)%32)
    auto loadrows = [&](float* wA, float* wB) {
        #pragma unroll
        for (int k = 0; k < 32; k++) wA[k] = wl[rowA * WROW + k];
        #pragma unroll
        for (int k = 0; k < 32; k++) wB[k] = wl[rowB * WROW + k];
    };

    float wA[32], wB[32];

    // ---- phase 1: layer-0 input projections (t-parallel, ILP-rich) ----
    stage(w_ih0, 4096);
    __syncthreads();
    loadrows(wA, wB);
    float bA = b_ih0[rowA] + b_hh0[rowA];
    float bB = b_ih0[rowB] + b_hh0[rowB];
    float xrow[T_STEPS];
    #pragma unroll
    for (int t = 0; t < T_STEPS; t++)
        xrow[t] = gat_out[((size_t)n * T_STEPS + t) * HID + j];
    float gxa[T_STEPS], gxb[T_STEPS];
    #pragma unroll
    for (int t = 0; t < T_STEPS; t++) {
        float a = bA, b = bB;
        #pragma unroll
        for (int k = 0; k < 32; k++) {
            float xk = rdlane(xrow[t], k);
            a = fmaf(xk, wA[k], a);
            b = fmaf(xk, wB[k], b);
        }
        gxa[t] = a; gxb[t] = b;
    }
    __syncthreads();

    // ---- phase 2: layer-0 recurrence ----
    stage(w_hh0, 4096);
    __syncthreads();
    loadrows(wA, wB);
    float h = 0.0f, c = 0.0f;
    float h0s[T_STEPS];
    #pragma unroll
    for (int t = 0; t < T_STEPS; t++) {
        float gA0 = gxa[t], gB0 = gxb[t], gA1 = 0.0f, gB1 = 0.0f;
        #pragma unroll
        for (int k = 0; k < 16; k++) {
            float h0 = rdlane(h, k), h1 = rdlane(h, k + 16);
            gA0 = fmaf(h0, wA[k], gA0);      gA1 = fmaf(h1, wA[k + 16], gA1);
            gB0 = fmaf(h0, wB[k], gB0);      gB1 = fmaf(h1, wB[k + 16], gB1);
        }
        float gA = gA0 + gA1, gB = gB0 + gB1;
        float oA = __shfl_xor(gA, 32, 64);
        float oB = __shfl_xor(gB, 32, 64);
        float gi = half ? oA : gA;
        float gf = half ? oB : gB;
        float gg = half ? gA : oA;
        float go = half ? gB : oB;
        c = sigm(gf) * c + sigm(gi) * tanh_f(gg);
        h = sigm(go) * tanh_f(c);
        h0s[t] = h;
    }
    __syncthreads();

    // ---- phase 3: layer-1 input projections from h0s ----
    stage(w_ih1, 4096);
    __syncthreads();
    loadrows(wA, wB);
    float bA1 = b_ih1[rowA] + b_hh1[rowA];
    float bB1 = b_ih1[rowB] + b_hh1[rowB];
    #pragma unroll
    for (int t = 0; t < T_STEPS; t++) {
        float a = bA1, b = bB1;
        #pragma unroll
        for (int k = 0; k < 32; k++) {
            float xk = rdlane(h0s[t], k);
            a = fmaf(xk, wA[k], a);
            b = fmaf(xk, wB[k], b);
        }
        gxa[t] = a; gxb[t] = b;
    }
    __syncthreads();

    // ---- phase 4: layer-1 recurrence ----
    stage(w_hh1, 4096);
    __syncthreads();
    loadrows(wA, wB);
    h = 0.0f; c = 0.0f;
    #pragma unroll
    for (int t = 0; t < T_STEPS; t++) {
        float gA0 = gxa[t], gB0 = gxb[t], gA1 = 0.0f, gB1 = 0.0f;
        #pragma unroll
        for (int k = 0; k < 16; k++) {
            float h0 = rdlane(h, k), h1 = rdlane(h, k + 16);
            gA0 = fmaf(h0, wA[k], gA0);      gA1 = fmaf(h1, wA[k + 16], gA1);
            gB0 = fmaf(h0, wB[k], gB0);      gB1 = fmaf(h1, wB[k + 16], gB1);
        }
        float gA = gA0 + gA1, gB = gB0 + gB1;
        float oA = __shfl_xor(gA, 32, 64);
        float oB = __shfl_xor(gB, 32, 64);
        float gi = half ? oA : gA;
        float gf = half ? oB : gB;
        float gg = half ? gA : oA;
        float go = half ? gB : oB;
        c = sigm(gf) * c + sigm(gi) * tanh_f(gg);
        h = sigm(go) * tanh_f(c);
    }
    __syncthreads();

    // ---- phase 5: FC head ----
    stage(fc_w, OUT_F * HID);    // 768 floats
    __syncthreads();
    int o = (lane < OUT_F) ? lane : (OUT_F - 1);   // lanes >=24 broadcast row 23
    float acc = fc_b[o];
    #pragma unroll
    for (int k = 0; k < 32; k++) {
        float hk = rdlane(h, k);
        acc = fmaf(hk, wl[o * WROW + k], acc);
    }
    if (lane < OUT_F) out[(size_t)n * OUT_F + lane] = acc;
}

// ---------------------------------------------------------------------------
extern "C" void kernel_launch(void* const* d_in, const int* in_sizes, int n_in,
                              void* d_out, int out_size, void* d_ws, size_t ws_size,
                              hipStream_t stream) {
    (void)in_sizes; (void)n_in; (void)out_size; (void)ws_size;
    const float* X       = (const float*)d_in[0];
    const int*   ei      = (const int*)d_in[1];
    const float* gat_w   = (const float*)d_in[2];
    const float* att_src = (const float*)d_in[3];
    const float* att_dst = (const float*)d_in[4];
    const float* gat_b   = (const float*)d_in[5];
    const float* w_ih0   = (const float*)d_in[6];
    const float* w_hh0   = (const float*)d_in[7];
    const float* b_ih0   = (const float*)d_in[8];
    const float* b_hh0   = (const float*)d_in[9];
    const float* w_ih1   = (const float*)d_in[10];
    const float* w_hh1   = (const float*)d_in[11];
    const float* b_ih1   = (const float*)d_in[12];
    const float* b_hh1   = (const float*)d_in[13];
    const float* fc_w    = (const float*)d_in[14];
    const float* fc_b    = (const float*)d_in[15];
    float* out = (float*)d_out;

    char* ws = (char*)d_ws;
    size_t off = 0;
    auto alloc_f = [&](size_t n) { float* p = (float*)(ws + off); off += n * sizeof(float); return p; };
    auto alloc_i = [&](size_t n) { int* p = (int*)(ws + off); off += n * sizeof(int); return p; };

    float*  gat_out = alloc_f((size_t)NT * HID);        // 4.6 MB
    float2* Xt      = (float2*)alloc_f((size_t)NT * 2); // 288 KB
    float*  proj    = alloc_f(32);
    int* row_start = alloc_i(N_NODES + 1);
    int* csr_src   = alloc_i(E_TOT);

    k_graph<<<38, 1024, 0, stream>>>(ei, X, gat_w, att_src, att_dst,
                                     Xt, proj, row_start, csr_src);
    k_gat<<<NT / 4, 256, 0, stream>>>(Xt, row_start, csr_src, proj,
                                      gat_w, gat_b, gat_out);
    k_lstm<<<N_NODES / 4, 256, 0, stream>>>(gat_out, w_ih0, w_hh0, b_ih0, b_hh0,
                                            w_ih1, w_hh1, b_ih1, b_hh1,
                                            fc_w, fc_b, out);
}

// Round 12
// 149.497 us; speedup vs baseline: 1.2776x; 1.2776x over previous
//
#include <hip/hip_runtime.h>
#include <math.h>

#define N_NODES 3000
#define T_STEPS 12
#define F_INP 2
#define HEADS 8
#define HID 32
#define E_EDGES 32000
#define E_TOT (E_EDGES + N_NODES)   // 35000 with self-loops
#define NEG_SLOPE 0.2f
#define OUT_F 24                    // F_OUT * T_OUT
#define SLOTS 48                    // bucket capacity per dst (max indeg ~30)
#define CHUNKS 6                    // 8 slots x 6 chunks = 48 edges in regs
#define NT (N_NODES * T_STEPS)      // 36000
#define WROW 33                     // LDS row stride (+1 pad -> conflict-free)

__device__ __forceinline__ float sigm(float x) {
    return 1.0f / (1.0f + __expf(-x));
}
__device__ __forceinline__ float tanh_f(float x) {
    return 1.0f - 2.0f / (__expf(2.0f * x) + 1.0f);
}
// broadcast lane l's value via scalar pipe (v_readlane). CONVERGENT: call at
// full exec only (round-4 post-mortem).
__device__ __forceinline__ float rdlane(float v, int l) {
    return __int_as_float(__builtin_amdgcn_readlane(__float_as_int(v), l));
}

// ---------------------------------------------------------------------------
// k_pre: ONE parallel kernel for all graph prep (round-11 post-mortem: the
// single-block CSR serialized ~100k LDS-atomic/scatter ops on one CU = 60 us;
// round-10's scan+scatter kernels cost ~26 us in launches+gaps). Buckets
// need NO scan and NO second pass: slot = atomicAdd(cnt[dst]) (global,
// multi-block), eslot[dst*SLOTS+slot] = src. cnt is zeroed by a preceding
// hipMemsetAsync (graph-capture legal; the harness itself uses it).
// blocks 0..34: edge bucketing; 35..70: Xt[t][n] transpose; 71: proj.
// ---------------------------------------------------------------------------
__global__ __launch_bounds__(1024) void k_pre(const int* __restrict__ ei,
                                              const float* __restrict__ X,
                                              const float* __restrict__ gat_w,
                                              const float* __restrict__ att_src,
                                              const float* __restrict__ att_dst,
                                              float2* __restrict__ Xt,
                                              float* __restrict__ proj,
                                              int* __restrict__ cnt,
                                              int* __restrict__ eslot) {
    int tid = threadIdx.x, b = blockIdx.x;
    if (b < 35) {
        int i = b * 1024 + tid;
        if (i < E_TOT) {
            int s, d;
            if (i < E_EDGES) { s = ei[i]; d = ei[E_EDGES + i]; }
            else             { s = i - E_EDGES; d = s; }
            int slot = atomicAdd(&cnt[d], 1);
            if (slot < SLOTS) eslot[d * SLOTS + slot] = s;   // P(overflow)~1e-16
        }
    } else if (b <= 70) {
        int i = (b - 35) * 1024 + tid;   // i = n*T + t
        if (i < NT) {
            int n = i / T_STEPS, t = i - n * T_STEPS;
            float2 v = *(const float2*)&X[(size_t)i * 2];
            Xt[(size_t)t * N_NODES + n] = v;
        }
    } else {
        if (tid < 32) {
            int h = tid & 7, w = tid >> 3;
            const float* att = (w < 2) ? att_src : att_dst;
            int f = w & 1;
            float s = 0.0f;
            for (int c = 0; c < 32; c++)
                s += gat_w[((h * 32 + c) * 2) + f] * att[h * 32 + c];
            proj[w * 8 + h] = s;
        }
    }
}

// ---------------------------------------------------------------------------
// k_gat: one wave64 per (t,n). lanes = 8 heads x 8 slots. Edge values in
// registers, reductions via shfl_xor(1,2,4); head-sum broadcast via
// v_readlane AT FULL EXEC (round-4 fix). Reads Xt (L1-resident 24 KB plane
// per t) and the fixed-slot buckets (no CSR). gat_out layout: [n][t][c]
// ---------------------------------------------------------------------------
__global__ __launch_bounds__(256) void k_gat(const float2* __restrict__ Xt,
                                             const int* __restrict__ cnt,
                                             const int* __restrict__ eslot,
                                             const float* __restrict__ proj,
                                             const float* __restrict__ gat_w,
                                             const float* __restrict__ gat_b,
                                             float* __restrict__ gat_out) {
    int pair = blockIdx.x * 4 + (threadIdx.x >> 6);   // t*N + n
    int t = pair / N_NODES, n = pair - t * N_NODES;
    int lane = threadIdx.x & 63;
    int h = lane >> 3, slot = lane & 7;
    int rs = n * SLOTS;
    int deg = cnt[n];                    // >= 1 (self-loop), <= ~31 << SLOTS
    const float2* Xp = Xt + (size_t)t * N_NODES;
    float ps0 = proj[h], ps1 = proj[8 + h];
    float pd0 = proj[16 + h], pd1 = proj[24 + h];
    float2 xd = Xp[n];
    float ad = fmaf(xd.x, pd0, xd.y * pd1);

    float x0c[CHUNKS], x1c[CHUNKS], sc[CHUNKS];
    float m = -1e30f;
    #pragma unroll
    for (int c = 0; c < CHUNKS; c++) {
        if (8 * c < deg) {                       // wave-uniform branch
            int e = slot + 8 * c;
            int idx = rs + (e < deg ? e : deg - 1);
            int src = eslot[idx];
            float2 xv = Xp[src];
            x0c[c] = xv.x; x1c[c] = xv.y;
            float s = fmaf(xv.x, ps0, fmaf(xv.y, ps1, ad));
            s = (s > 0.0f) ? s : NEG_SLOPE * s;
            sc[c] = (e < deg) ? s : -1e30f;
            m = fmaxf(m, sc[c]);
        } else { x0c[c] = 0.0f; x1c[c] = 0.0f; sc[c] = -1e30f; }
    }
    m = fmaxf(m, __shfl_xor(m, 1, 64));
    m = fmaxf(m, __shfl_xor(m, 2, 64));
    m = fmaxf(m, __shfl_xor(m, 4, 64));

    float den = 0.0f, S0 = 0.0f, S1 = 0.0f;
    #pragma unroll
    for (int c = 0; c < CHUNKS; c++) {
        if (8 * c < deg) {
            float a = __expf(sc[c] - m);          // masked slots: exp(-1e30)=0
            den += a;
            S0 = fmaf(a, x0c[c], S0);
            S1 = fmaf(a, x1c[c], S1);
        }
    }
    #pragma unroll
    for (int mm = 1; mm <= 4; mm <<= 1) {
        den += __shfl_xor(den, mm, 64);
        S0  += __shfl_xor(S0,  mm, 64);
        S1  += __shfl_xor(S1,  mm, 64);
    }
    float inv = 0.125f / den;
    float v0 = S0 * inv, v1 = S1 * inv;

    // per-head broadcasts at FULL EXEC (readlane is convergent; round-4 fix)
    float a0[HEADS], a1[HEADS];
    #pragma unroll
    for (int hh = 0; hh < HEADS; hh++) {
        a0[hh] = rdlane(v0, hh * 8);
        a1[hh] = rdlane(v1, hh * 8);
    }

    // branch-free projection: all lanes compute, lanes 0..31 store
    int cc = lane & 31;
    float acc = gat_b[cc];
    #pragma unroll
    for (int hh = 0; hh < HEADS; hh++) {
        float2 g = *(const float2*)&gat_w[(hh * 32 + cc) * 2];
        acc = fmaf(a0[hh], g.x, fmaf(a1[hh], g.y, acc));
    }
    if (lane < 32)
        gat_out[((size_t)n * T_STEPS + t) * HID + cc] = acc;
}

// ---------------------------------------------------------------------------
// k_lstm (v3, the measured-46.7us config, reverted from v5): fused 2-layer
// LSTM + FC. Block = 256 thr = 4 waves = 4 nodes. Weights staged COALESCED
// into LDS phase-by-phase (round-7 lesson: per-lane row-strided global loads
// cost 64 cache lines/instr). LDS rows stride 33 -> per-lane row reads
// conflict-free. Split-gate: half 0 owns (i,f), half 1 owns (g,o); h
// broadcast via v_readlane; split-k 2x16 fma chains. round-11's
// waves_per_eu(3,3) showed no gain (possibly -5us) -> dropped.
// ---------------------------------------------------------------------------
__global__ __launch_bounds__(256, 3)
void k_lstm(const float* __restrict__ gat_out,  // [n][t][32]
            const float* __restrict__ w_ih0,
            const float* __restrict__ w_hh0,
            const float* __restrict__ b_ih0,
            const float* __restrict__ b_hh0,
            const float* __restrict__ w_ih1,
            const float* __restrict__ w_hh1,
            const float* __restrict__ b_ih1,
            const float* __restrict__ b_hh1,
            const float* __restrict__ fc_w,
            const float* __restrict__ fc_b,
            float* __restrict__ out) {          // [n][24]
    __shared__ float wl[128 * WROW];            // 16.9 KB, reused 5x
    int tid = threadIdx.x;
    int lane = tid & 63;
    int n = blockIdx.x * 4 + (tid >> 6);
    int j = lane & 31, half = lane >> 5;
    int rowA = half * 64 + j;        // gate i (half0) / g (half1)
    int rowB = rowA + 32;            // gate f (half0) / o (half1)

    // coalesced global -> LDS stage (float4 loads, scalar LDS writes)
    auto stage = [&](const float* __restrict__ src, int nfloats) {
        for (int base = tid * 4; base < nfloats; base += 1024) {
            float4 v = *(const float4*)&src[base];
            float* d = &wl[(base >> 5) * WROW + (base & 31)];
            d[0] = v.x; d[1] = v.y; d[2] = v.z; d[3] = v.w;
        }
    };
    // per-lane row fetch from LDS (conflict-free: bank = (row+k)%32)
    auto loadrows = [&](float* wA, float* wB) {
        #pragma unroll
        for (int k = 0; k < 32; k++) wA[k] = wl[rowA * WROW + k];
        #pragma unroll
        for (int k = 0; k < 32; k++) wB[k] = wl[rowB * WROW + k];
    };

    float wA[32], wB[32];

    // ---- phase 1: layer-0 input projections (t-parallel, ILP-rich) ----
    stage(w_ih0, 4096);
    __syncthreads();
    loadrows(wA, wB);
    float bA = b_ih0[rowA] + b_hh0[rowA];
    float bB = b_ih0[rowB] + b_hh0[rowB];
    float xrow[T_STEPS];
    #pragma unroll
    for (int t = 0; t < T_STEPS; t++)
        xrow[t] = gat_out[((size_t)n * T_STEPS + t) * HID + j];
    float gxa[T_STEPS], gxb[T_STEPS];
    #pragma unroll
    for (int t = 0; t < T_STEPS; t++) {
        float a = bA, b = bB;
        #pragma unroll
        for (int k = 0; k < 32; k++) {
            float xk = rdlane(xrow[t], k);
            a = fmaf(xk, wA[k], a);
            b = fmaf(xk, wB[k], b);
        }
        gxa[t] = a; gxb[t] = b;
    }
    __syncthreads();

    // ---- phase 2: layer-0 recurrence ----
    stage(w_hh0, 4096);
    __syncthreads();
    loadrows(wA, wB);
    float h = 0.0f, c = 0.0f;
    float h0s[T_STEPS];
    #pragma unroll
    for (int t = 0; t < T_STEPS; t++) {
        float gA0 = gxa[t], gB0 = gxb[t], gA1 = 0.0f, gB1 = 0.0f;
        #pragma unroll
        for (int k = 0; k < 16; k++) {
            float h0 = rdlane(h, k), h1 = rdlane(h, k + 16);
            gA0 = fmaf(h0, wA[k], gA0);      gA1 = fmaf(h1, wA[k + 16], gA1);
            gB0 = fmaf(h0, wB[k], gB0);      gB1 = fmaf(h1, wB[k + 16], gB1);
        }
        float gA = gA0 + gA1, gB = gB0 + gB1;
        float oA = __shfl_xor(gA, 32, 64);
        float oB = __shfl_xor(gB, 32, 64);
        float gi = half ? oA : gA;
        float gf = half ? oB : gB;
        float gg = half ? gA : oA;
        float go = half ? gB : oB;
        c = sigm(gf) * c + sigm(gi) * tanh_f(gg);
        h = sigm(go) * tanh_f(c);
        h0s[t] = h;
    }
    __syncthreads();

    // ---- phase 3: layer-1 input projections from h0s ----
    stage(w_ih1, 4096);
    __syncthreads();
    loadrows(wA, wB);
    float bA1 = b_ih1[rowA] + b_hh1[rowA];
    float bB1 = b_ih1[rowB] + b_hh1[rowB];
    #pragma unroll
    for (int t = 0; t < T_STEPS; t++) {
        float a = bA1, b = bB1;
        #pragma unroll
        for (int k = 0; k < 32; k++) {
            float xk = rdlane(h0s[t], k);
            a = fmaf(xk, wA[k], a);
            b = fmaf(xk, wB[k], b);
        }
        gxa[t] = a; gxb[t] = b;
    }
    __syncthreads();

    // ---- phase 4: layer-1 recurrence ----
    stage(w_hh1, 4096);
    __syncthreads();
    loadrows(wA, wB);
    h = 0.0f; c = 0.0f;
    #pragma unroll
    for (int t = 0; t < T_STEPS; t++) {
        float gA0 = gxa[t], gB0 = gxb[t], gA1 = 0.0f, gB1 = 0.0f;
        #pragma unroll
        for (int k = 0; k < 16; k++) {
            float h0 = rdlane(h, k), h1 = rdlane(h, k + 16);
            gA0 = fmaf(h0, wA[k], gA0);      gA1 = fmaf(h1, wA[k + 16], gA1);
            gB0 = fmaf(h0, wB[k], gB0);      gB1 = fmaf(h1, wB[k + 16], gB1);
        }
        float gA = gA0 + gA1, gB = gB0 + gB1;
        float oA = __shfl_xor(gA, 32, 64);
        float oB = __shfl_xor(gB, 32, 64);
        float gi = half ? oA : gA;
        float gf = half ? oB : gB;
        float gg = half ? gA : oA;
        float go = half ? gB : oB;
        c = sigm(gf) * c + sigm(gi) * tanh_f(gg);
        h = sigm(go) * tanh_f(c);
    }
    __syncthreads();

    // ---- phase 5: FC head ----
    stage(fc_w, OUT_F * HID);    // 768 floats
    __syncthreads();
    int o = (lane < OUT_F) ? lane : (OUT_F - 1);   // lanes >=24 broadcast row 23
    float acc = fc_b[o];
    #pragma unroll
    for (int k = 0; k < 32; k++) {
        float hk = rdlane(h, k);
        acc = fmaf(hk, wl[o * WROW + k], acc);
    }
    if (lane < OUT_F) out[(size_t)n * OUT_F + lane] = acc;
}

// ---------------------------------------------------------------------------
extern "C" void kernel_launch(void* const* d_in, const int* in_sizes, int n_in,
                              void* d_out, int out_size, void* d_ws, size_t ws_size,
                              hipStream_t stream) {
    (void)in_sizes; (void)n_in; (void)out_size; (void)ws_size;
    const float* X       = (const float*)d_in[0];
    const int*   ei      = (const int*)d_in[1];
    const float* gat_w   = (const float*)d_in[2];
    const float* att_src = (const float*)d_in[3];
    const float* att_dst = (const float*)d_in[4];
    const float* gat_b   = (const float*)d_in[5];
    const float* w_ih0   = (const float*)d_in[6];
    const float* w_hh0   = (const float*)d_in[7];
    const float* b_ih0   = (const float*)d_in[8];
    const float* b_hh0   = (const float*)d_in[9];
    const float* w_ih1   = (const float*)d_in[10];
    const float* w_hh1   = (const float*)d_in[11];
    const float* b_ih1   = (const float*)d_in[12];
    const float* b_hh1   = (const float*)d_in[13];
    const float* fc_w    = (const float*)d_in[14];
    const float* fc_b    = (const float*)d_in[15];
    float* out = (float*)d_out;

    char* ws = (char*)d_ws;
    size_t off = 0;
    auto alloc_f = [&](size_t n) { float* p = (float*)(ws + off); off += n * sizeof(float); return p; };
    auto alloc_i = [&](size_t n) { int* p = (int*)(ws + off); off += n * sizeof(int); return p; };

    float*  gat_out = alloc_f((size_t)NT * HID);        // 4.6 MB
    float2* Xt      = (float2*)alloc_f((size_t)NT * 2); // 288 KB
    float*  proj    = alloc_f(32);
    int* cnt   = alloc_i(N_NODES);
    int* eslot = alloc_i((size_t)N_NODES * SLOTS);      // 576 KB

    hipMemsetAsync(cnt, 0, N_NODES * sizeof(int), stream);
    k_pre<<<72, 1024, 0, stream>>>(ei, X, gat_w, att_src, att_dst,
                                   Xt, proj, cnt, eslot);
    k_gat<<<NT / 4, 256, 0, stream>>>(Xt, cnt, eslot, proj,
                                      gat_w, gat_b, gat_out);
    k_lstm<<<N_NODES / 4, 256, 0, stream>>>(gat_out, w_ih0, w_hh0, b_ih0, b_hh0,
                                            w_ih1, w_hh1, b_ih1, b_hh1,
                                            fc_w, fc_b, out);
}

// Round 13
// 146.678 us; speedup vs baseline: 1.3022x; 1.0192x over previous
//
#include <hip/hip_runtime.h>
#include <math.h>

#define N_NODES 3000
#define T_STEPS 12
#define F_INP 2
#define HEADS 8
#define HID 32
#define E_EDGES 32000
#define E_TOT (E_EDGES + N_NODES)   // 35000 with self-loops
#define NEG_SLOPE 0.2f
#define OUT_F 24                    // F_OUT * T_OUT
#define SLOTS 48                    // bucket capacity per dst (max indeg ~30)
#define CHUNKS 6                    // 8 slots x 6 chunks = 48 edges in regs
#define NT (N_NODES * T_STEPS)      // 36000
#define WROW 33                     // LDS row stride (+1 pad -> conflict-free)

__device__ __forceinline__ float sigm(float x) {
    return 1.0f / (1.0f + __expf(-x));
}
__device__ __forceinline__ float tanh_f(float x) {
    return 1.0f - 2.0f / (__expf(2.0f * x) + 1.0f);
}
// broadcast lane l's value via scalar pipe (v_readlane). CONVERGENT: call at
// full exec only (round-4 post-mortem).
__device__ __forceinline__ float rdlane(float v, int l) {
    return __int_as_float(__builtin_amdgcn_readlane(__float_as_int(v), l));
}

// ---------------------------------------------------------------------------
// k_pre: ONE parallel kernel for all graph prep (round-11 lesson: never
// serialize graph-sized work on one CU). Fixed-slot buckets need no scan:
// slot = atomicAdd(cnt[dst]); eslot[dst*SLOTS+slot] = src. cnt zeroed by a
// preceding hipMemsetAsync. blocks 0..34 bucket edges; 35..70 transpose Xt;
// 71 computes proj.
// ---------------------------------------------------------------------------
__global__ __launch_bounds__(1024) void k_pre(const int* __restrict__ ei,
                                              const float* __restrict__ X,
                                              const float* __restrict__ gat_w,
                                              const float* __restrict__ att_src,
                                              const float* __restrict__ att_dst,
                                              float2* __restrict__ Xt,
                                              float* __restrict__ proj,
                                              int* __restrict__ cnt,
                                              int* __restrict__ eslot) {
    int tid = threadIdx.x, b = blockIdx.x;
    if (b < 35) {
        int i = b * 1024 + tid;
        if (i < E_TOT) {
            int s, d;
            if (i < E_EDGES) { s = ei[i]; d = ei[E_EDGES + i]; }
            else             { s = i - E_EDGES; d = s; }
            int slot = atomicAdd(&cnt[d], 1);
            if (slot < SLOTS) eslot[d * SLOTS + slot] = s;   // P(overflow)~1e-16
        }
    } else if (b <= 70) {
        int i = (b - 35) * 1024 + tid;   // i = n*T + t
        if (i < NT) {
            int n = i / T_STEPS, t = i - n * T_STEPS;
            float2 v = *(const float2*)&X[(size_t)i * 2];
            Xt[(size_t)t * N_NODES + n] = v;
        }
    } else {
        if (tid < 32) {
            int h = tid & 7, w = tid >> 3;
            const float* att = (w < 2) ? att_src : att_dst;
            int f = w & 1;
            float s = 0.0f;
            for (int c = 0; c < 32; c++)
                s += gat_w[((h * 32 + c) * 2) + f] * att[h * 32 + c];
            proj[w * 8 + h] = s;
        }
    }
}

// ---------------------------------------------------------------------------
// k_fused: GAT (12 t-steps) + 2-layer LSTM + FC in ONE kernel.
// Block = 256 thr = 4 waves = 4 nodes; one wave owns node n end-to-end, so
// the GAT output xrow[12] stays in registers (kills the 9.2 MB gat_out
// roundtrip + one dispatch's ~10 us overhead).
//
// GAT phase (per wave): lanes = 8 heads x 8 slots; neighbor indices loaded
// ONCE (t-invariant), per t: L1 gathers from the 24 KB Xt plane (only 8
// distinct addresses/instr -- head groups alias), shfl_xor reductions,
// per-head broadcast via readlane at FULL EXEC (round-4 fix).
//
// LSTM phases: weights staged coalesced into LDS (round-7 lesson), rows at
// stride 33 (conflict-free), split-gate halves, split-k 2x16 chains.
// NEW (round-12 post-mortem): asm-pin wA/wB after each loadrows. Three
// rounds showed the allocator capping arch VGPRs at 56-68 and ~2x dynamic
// instruction bloat with zero scratch traffic -- best explanation is LDS
// rematerialization (ds_read at every weight use) or AGPR shuffling; the
// opaque "+v" constraint forbids both (value must live in an arch VGPR).
// ---------------------------------------------------------------------------
__global__ __launch_bounds__(256, 3)
void k_fused(const float2* __restrict__ Xt,
             const int* __restrict__ cnt,
             const int* __restrict__ eslot,
             const float* __restrict__ proj,
             const float* __restrict__ gat_w,
             const float* __restrict__ gat_b,
             const float* __restrict__ w_ih0,
             const float* __restrict__ w_hh0,
             const float* __restrict__ b_ih0,
             const float* __restrict__ b_hh0,
             const float* __restrict__ w_ih1,
             const float* __restrict__ w_hh1,
             const float* __restrict__ b_ih1,
             const float* __restrict__ b_hh1,
             const float* __restrict__ fc_w,
             const float* __restrict__ fc_b,
             float* __restrict__ out) {          // [n][24]
    __shared__ float wl[128 * WROW];             // 16.9 KB, reused 5x
    int tid = threadIdx.x;
    int lane = tid & 63;
    int n = blockIdx.x * 4 + (tid >> 6);
    int j = lane & 31, half = lane >> 5;
    int rowA = half * 64 + j;        // gate i (half0) / g (half1)
    int rowB = rowA + 32;            // gate f (half0) / o (half1)

    auto stage = [&](const float* __restrict__ src, int nfloats) {
        for (int base = tid * 4; base < nfloats; base += 1024) {
            float4 v = *(const float4*)&src[base];
            float* d = &wl[(base >> 5) * WROW + (base & 31)];
            d[0] = v.x; d[1] = v.y; d[2] = v.z; d[3] = v.w;
        }
    };
    auto loadrows = [&](float* wA, float* wB) {
        #pragma unroll
        for (int k = 0; k < 32; k++) wA[k] = wl[rowA * WROW + k];
        #pragma unroll
        for (int k = 0; k < 32; k++) wB[k] = wl[rowB * WROW + k];
        // pin to arch VGPRs: forbid LDS remat / AGPR round-trips
        #pragma unroll
        for (int k = 0; k < 32; k++)
            asm volatile("" : "+v"(wA[k]), "+v"(wB[k]));
    };

    // issue the first weight stage早 -- its latency hides under the GAT phase
    stage(w_ih0, 4096);

    // ================= GAT phase: xrow[t] in registers =================
    float xrow[T_STEPS];
    {
        int hh8 = lane >> 3, slot = lane & 7;
        int deg = cnt[n];
        deg = (deg < SLOTS) ? deg : SLOTS;       // safety clamp (P~1e-16)
        int srcs[CHUNKS];
        #pragma unroll
        for (int c = 0; c < CHUNKS; c++) {
            int e = slot + 8 * c;
            int idx = n * SLOTS + ((e < deg) ? e : deg - 1);
            srcs[c] = (8 * c < deg) ? eslot[idx] : 0;    // wave-uniform cond
        }
        float ps0 = proj[hh8], ps1 = proj[8 + hh8];
        float pd0 = proj[16 + hh8], pd1 = proj[24 + hh8];
        float gb = gat_b[j];
        float gw0[HEADS], gw1[HEADS];
        #pragma unroll
        for (int hh = 0; hh < HEADS; hh++) {
            float2 g = *(const float2*)&gat_w[(hh * 32 + j) * 2];
            gw0[hh] = g.x; gw1[hh] = g.y;
        }
        for (int t = 0; t < T_STEPS; t++) {
            const float2* Xp = Xt + (size_t)t * N_NODES;
            float2 xd = Xp[n];
            float ad = fmaf(xd.x, pd0, xd.y * pd1);
            float x0c[CHUNKS], x1c[CHUNKS], sc[CHUNKS];
            float m = -1e30f;
            #pragma unroll
            for (int c = 0; c < CHUNKS; c++) {
                if (8 * c < deg) {
                    int e = slot + 8 * c;
                    float2 xv = Xp[srcs[c]];
                    x0c[c] = xv.x; x1c[c] = xv.y;
                    float s = fmaf(xv.x, ps0, fmaf(xv.y, ps1, ad));
                    s = (s > 0.0f) ? s : NEG_SLOPE * s;
                    sc[c] = (e < deg) ? s : -1e30f;
                    m = fmaxf(m, sc[c]);
                } else { x0c[c] = 0.0f; x1c[c] = 0.0f; sc[c] = -1e30f; }
            }
            m = fmaxf(m, __shfl_xor(m, 1, 64));
            m = fmaxf(m, __shfl_xor(m, 2, 64));
            m = fmaxf(m, __shfl_xor(m, 4, 64));
            float den = 0.0f, S0 = 0.0f, S1 = 0.0f;
            #pragma unroll
            for (int c = 0; c < CHUNKS; c++) {
                if (8 * c < deg) {
                    float a = __expf(sc[c] - m);
                    den += a;
                    S0 = fmaf(a, x0c[c], S0);
                    S1 = fmaf(a, x1c[c], S1);
                }
            }
            #pragma unroll
            for (int mm = 1; mm <= 4; mm <<= 1) {
                den += __shfl_xor(den, mm, 64);
                S0  += __shfl_xor(S0,  mm, 64);
                S1  += __shfl_xor(S1,  mm, 64);
            }
            float inv = 0.125f / den;
            float v0 = S0 * inv, v1 = S1 * inv;
            // per-head broadcast at FULL EXEC; all lanes compute projection
            float acc = gb;
            #pragma unroll
            for (int hh = 0; hh < HEADS; hh++) {
                float a0 = rdlane(v0, hh * 8);
                float a1 = rdlane(v1, hh * 8);
                acc = fmaf(a0, gw0[hh], fmaf(a1, gw1[hh], acc));
            }
            xrow[t] = acc;    // lane j holds out[j], replicated in halves
        }
    }
    __syncthreads();          // w_ih0 staged

    float wA[32], wB[32];

    // ---- phase 1: layer-0 input projections ----
    loadrows(wA, wB);
    float bA = b_ih0[rowA] + b_hh0[rowA];
    float bB = b_ih0[rowB] + b_hh0[rowB];
    float gxa[T_STEPS], gxb[T_STEPS];
    #pragma unroll
    for (int t = 0; t < T_STEPS; t++) {
        float a = bA, b = bB;
        #pragma unroll
        for (int k = 0; k < 32; k++) {
            float xk = rdlane(xrow[t], k);
            a = fmaf(xk, wA[k], a);
            b = fmaf(xk, wB[k], b);
        }
        gxa[t] = a; gxb[t] = b;
    }
    __syncthreads();

    // ---- phase 2: layer-0 recurrence ----
    stage(w_hh0, 4096);
    __syncthreads();
    loadrows(wA, wB);
    float h = 0.0f, c = 0.0f;
    float h0s[T_STEPS];
    #pragma unroll
    for (int t = 0; t < T_STEPS; t++) {
        float gA0 = gxa[t], gB0 = gxb[t], gA1 = 0.0f, gB1 = 0.0f;
        #pragma unroll
        for (int k = 0; k < 16; k++) {
            float h0 = rdlane(h, k), h1 = rdlane(h, k + 16);
            gA0 = fmaf(h0, wA[k], gA0);      gA1 = fmaf(h1, wA[k + 16], gA1);
            gB0 = fmaf(h0, wB[k], gB0);      gB1 = fmaf(h1, wB[k + 16], gB1);
        }
        float gA = gA0 + gA1, gB = gB0 + gB1;
        float oA = __shfl_xor(gA, 32, 64);
        float oB = __shfl_xor(gB, 32, 64);
        float gi = half ? oA : gA;
        float gf = half ? oB : gB;
        float gg = half ? gA : oA;
        float go = half ? gB : oB;
        c = sigm(gf) * c + sigm(gi) * tanh_f(gg);
        h = sigm(go) * tanh_f(c);
        h0s[t] = h;
    }
    __syncthreads();

    // ---- phase 3: layer-1 input projections ----
    stage(w_ih1, 4096);
    __syncthreads();
    loadrows(wA, wB);
    float bA1 = b_ih1[rowA] + b_hh1[rowA];
    float bB1 = b_ih1[rowB] + b_hh1[rowB];
    #pragma unroll
    for (int t = 0; t < T_STEPS; t++) {
        float a = bA1, b = bB1;
        #pragma unroll
        for (int k = 0; k < 32; k++) {
            float xk = rdlane(h0s[t], k);
            a = fmaf(xk, wA[k], a);
            b = fmaf(xk, wB[k], b);
        }
        gxa[t] = a; gxb[t] = b;
    }
    __syncthreads();

    // ---- phase 4: layer-1 recurrence ----
    stage(w_hh1, 4096);
    __syncthreads();
    loadrows(wA, wB);
    h = 0.0f; c = 0.0f;
    #pragma unroll
    for (int t = 0; t < T_STEPS; t++) {
        float gA0 = gxa[t], gB0 = gxb[t], gA1 = 0.0f, gB1 = 0.0f;
        #pragma unroll
        for (int k = 0; k < 16; k++) {
            float h0 = rdlane(h, k), h1 = rdlane(h, k + 16);
            gA0 = fmaf(h0, wA[k], gA0);      gA1 = fmaf(h1, wA[k + 16], gA1);
            gB0 = fmaf(h0, wB[k], gB0);      gB1 = fmaf(h1, wB[k + 16], gB1);
        }
        float gA = gA0 + gA1, gB = gB0 + gB1;
        float oA = __shfl_xor(gA, 32, 64);
        float oB = __shfl_xor(gB, 32, 64);
        float gi = half ? oA : gA;
        float gf = half ? oB : gB;
        float gg = half ? gA : oA;
        float go = half ? gB : oB;
        c = sigm(gf) * c + sigm(gi) * tanh_f(gg);
        h = sigm(go) * tanh_f(c);
    }
    __syncthreads();

    // ---- phase 5: FC head ----
    stage(fc_w, OUT_F * HID);    // 768 floats
    __syncthreads();
    int o = (lane < OUT_F) ? lane : (OUT_F - 1);
    float acc = fc_b[o];
    #pragma unroll
    for (int k = 0; k < 32; k++) {
        float hk = rdlane(h, k);
        acc = fmaf(hk, wl[o * WROW + k], acc);
    }
    if (lane < OUT_F) out[(size_t)n * OUT_F + lane] = acc;
}

// ---------------------------------------------------------------------------
extern "C" void kernel_launch(void* const* d_in, const int* in_sizes, int n_in,
                              void* d_out, int out_size, void* d_ws, size_t ws_size,
                              hipStream_t stream) {
    (void)in_sizes; (void)n_in; (void)out_size; (void)ws_size;
    const float* X       = (const float*)d_in[0];
    const int*   ei      = (const int*)d_in[1];
    const float* gat_w   = (const float*)d_in[2];
    const float* att_src = (const float*)d_in[3];
    const float* att_dst = (const float*)d_in[4];
    const float* gat_b   = (const float*)d_in[5];
    const float* w_ih0   = (const float*)d_in[6];
    const float* w_hh0   = (const float*)d_in[7];
    const float* b_ih0   = (const float*)d_in[8];
    const float* b_hh0   = (const float*)d_in[9];
    const float* w_ih1   = (const float*)d_in[10];
    const float* w_hh1   = (const float*)d_in[11];
    const float* b_ih1   = (const float*)d_in[12];
    const float* b_hh1   = (const float*)d_in[13];
    const float* fc_w    = (const float*)d_in[14];
    const float* fc_b    = (const float*)d_in[15];
    float* out = (float*)d_out;

    char* ws = (char*)d_ws;
    size_t off = 0;
    auto alloc_f = [&](size_t n) { float* p = (float*)(ws + off); off += n * sizeof(float); return p; };
    auto alloc_i = [&](size_t n) { int* p = (int*)(ws + off); off += n * sizeof(int); return p; };

    float2* Xt   = (float2*)alloc_f((size_t)NT * 2);    // 288 KB
    float*  proj = alloc_f(32);
    int* cnt   = alloc_i(N_NODES);
    int* eslot = alloc_i((size_t)N_NODES * SLOTS);      // 576 KB

    hipMemsetAsync(cnt, 0, N_NODES * sizeof(int), stream);
    k_pre<<<72, 1024, 0, stream>>>(ei, X, gat_w, att_src, att_dst,
                                   Xt, proj, cnt, eslot);
    k_fused<<<N_NODES / 4, 256, 0, stream>>>(Xt, cnt, eslot, proj, gat_w, gat_b,
                                             w_ih0, w_hh0, b_ih0, b_hh0,
                                             w_ih1, w_hh1, b_ih1, b_hh1,
                                             fc_w, fc_b, out);
}